// Round 1
// 77.479 us; speedup vs baseline: 1.0235x; 1.0235x over previous
//
#include <hip/hip_runtime.h>
#include <hip/hip_bf16.h>

// SlidingGaussianWindow1d: B=16, T=256, C=64, NWIN=224, wsize=32.
// out[b,w,c,d] = corrcoef over t of (W[w,t]*x[b,t,c]), clipped to [-1,1].
//
// One (b,w) pair per block (3584 blocks, 256 thr). This revision removes the
// per-block runtime weight phase (weights are compile-time constants since the
// 1/(2a^2) scale cancels in A/A.max; alpha-NaN faithfulness kept via f=a^2/a^2),
// vectorizes staging to float4 loads, XOR-swizzles the LDS tile to kill the
// 8-way staging-write bank conflict, and cuts barriers 5 -> 3.

static constexpr int TT   = 256;   // time samples
static constexpr int CC   = 64;    // channels
static constexpr int NW   = 224;   // windows
static constexpr int U0   = 96;    // support window start (rolled coord)
static constexpr int KPAD = 72;    // Yt row stride in bf16 (144 B, 16B-mult)
static constexpr int PSTR = 68;    // Pred row stride in floats (breaks 0 mod 32)

typedef short bf16x8 __attribute__((ext_vector_type(8)));
typedef float f32x16 __attribute__((ext_vector_type(16)));

// e^{-d^2} for |d| = 0..12 (fp32; <=1e-43 underflows -> 0, contributes nothing)
static constexpr float EXPT[13] = {
    1.0f, 3.67879441e-1f, 1.83156389e-2f, 1.23409804e-4f,
    1.12535175e-7f, 1.38879439e-11f, 2.31952283e-16f, 5.24288566e-22f,
    1.60381089e-28f, 6.63700000e-36f, 0.0f, 0.0f, 0.0f };

struct alignas(16) WTab { float w[64]; };

// Wn[u] = (sum_{d=clamp(t-143)..clamp(t-112)} e^{-d^2}) / (sum_{|d|<=12} e^{-d^2}),
// t = U0+u.  Exactly the previous kernel's runtime computation with the alpha
// scale cancelled (it multiplied numerator and denominator equally).
static constexpr WTab make_wtab() {
    WTab t{};
    float tot = 0.f;
    for (int d = -12; d <= 12; ++d) tot += EXPT[d < 0 ? -d : d];
    for (int u = 0; u < 64; ++u) {
        int tc = U0 + u;
        int dlo = tc - 143; if (dlo < -12) dlo = -12;
        int dhi = tc - 112; if (dhi > 12)  dhi = 12;
        float s = 0.f;
        for (int d = dlo; d <= dhi; ++d) s += EXPT[d < 0 ? -d : d];
        t.w[u] = s / tot;
    }
    return t;
}
__device__ constexpr WTab WTAB = make_wtab();

__global__ __launch_bounds__(256, 8) void corr_kernel(const float* __restrict__ x,
                                                      const float* __restrict__ alpha,
                                                      float* __restrict__ out) {
    // Yt[c][u'] holds bf16(W[u]*x[t(u)][c]) at swizzled column
    // u' = u ^ (((c>>2)&7)<<3)  — XOR on the 8-elem chunk index keeps 16B
    // fragment reads contiguous/aligned and makes staging ds_write_b32
    // conflict-free (2-way) at row stride 36 dwords.
    __shared__ __align__(16) __hip_bfloat16 Yt[CC][KPAD];
    __shared__ __align__(16) float Pred[16][PSTR];   // per-g-group column sums
    __shared__ float colsum[CC];
    __shared__ float rdiag[CC];

    const int tid = threadIdx.x;
    const int blk = blockIdx.x;
    const int b = blk / NW;
    const int w = blk - b * NW;
    // cumulative roll S[w] = sum_{k<=w} (k-111) = (w+1)(w-222)/2
    const int S = ((w + 1) * (w - 222)) / 2;

    // alpha faithfulness: f = 1.0 for normal alpha; NaN for alpha in {0,inf,nan}
    // (reference produces all-NaN in those cases via inf/inf or 0/0).
    float aa = alpha[0]; aa = aa * aa;
    const float f = aa / aa;

    const int g   = tid >> 4;        // 0..15: u-pair group
    const int a   = tid & 15;        // channel quad index
    const int c4  = a << 2;          // first of 4 channels
    const int swz = (a & 7) << 3;    // column XOR for rows c4..c4+3 ((c>>2)&7)

    const float2* W2 = (const float2*)WTAB.w;
    float2 wlo = W2[g];
    float2 whi = W2[g + 16];
    wlo.x *= f; wlo.y *= f; whi.x *= f; whi.y *= f;

    // --- stage: each thread covers channels c4..c4+3 at u in {2g,2g+1,32+2g,32+2g+1}
    const float* xb = x + (size_t)b * (TT * CC);
    float ps[4] = {0.f, 0.f, 0.f, 0.f};
#pragma unroll
    for (int p = 0; p < 2; ++p) {
        const int u0 = 32 * p + 2 * g;
        const int t0 = (U0 + u0 - S) & 255;
        const int t1 = (U0 + u0 + 1 - S) & 255;
        const float4 v0 = *(const float4*)(xb + t0 * CC + c4);
        const float4 v1 = *(const float4*)(xb + t1 * CC + c4);
        const float wa = p ? whi.x : wlo.x;
        const float wb = p ? whi.y : wlo.y;
        const int uc = u0 ^ swz;
        const float e0[4] = {v0.x, v0.y, v0.z, v0.w};
        const float e1[4] = {v1.x, v1.y, v1.z, v1.w};
#pragma unroll
        for (int i = 0; i < 4; ++i) {
            __hip_bfloat16 h0 = __float2bfloat16(e0[i] * wa);
            __hip_bfloat16 h1 = __float2bfloat16(e1[i] * wb);
            // column sums from the QUANTIZED values (keeps corr diag == 1)
            ps[i] += __bfloat162float(h0) + __bfloat162float(h1);
            unsigned pk = ((unsigned)*(unsigned short*)&h1 << 16) |
                          (unsigned)*(unsigned short*)&h0;
            *(unsigned*)&Yt[c4 + i][uc] = pk;      // uc even -> 4B aligned
        }
    }
    {
        float4 psv = {ps[0], ps[1], ps[2], ps[3]};
        *(float4*)&Pred[g][c4] = psv;              // 272g+16a bytes: 16B aligned
    }
    __syncthreads();                               // barrier 1: Yt + Pred ready

    // --- Gram via MFMA: G = Y^T Y, 4 waves -> 2x2 grid of 32x32 tiles ---
    const int wv = tid >> 6, lane = tid & 63;
    const int ti = wv >> 1, tj = wv & 1;
    const int r32 = lane & 31, half = lane >> 5;
    const int sg = (r32 >> 2) & 7;                 // == ((row>>2)&7) for both rows

    f32x16 acc;
#pragma unroll
    for (int i = 0; i < 16; ++i) acc[i] = 0.f;
    const __hip_bfloat16* ya = &Yt[32 * ti + r32][0];
    const __hip_bfloat16* yb = &Yt[32 * tj + r32][0];
#pragma unroll
    for (int t = 0; t < 4; ++t) {
        const int off = ((2 * t + half) ^ sg) << 3;   // swizzled 8-elem chunk
        bf16x8 af = *(const bf16x8*)(ya + off);
        bf16x8 bf = *(const bf16x8*)(yb + off);
        acc = __builtin_amdgcn_mfma_f32_32x32x16_bf16(af, bf, acc, 0, 0, 0);
    }

    if (tid < CC) {
        float s = 0.f;
#pragma unroll
        for (int gg = 0; gg < 16; ++gg) s += Pred[gg][tid];
        colsum[tid] = s;
    }
    __syncthreads();                               // barrier 2: colsum ready

    // --- diag -> rsqrt(raw centered gram); invT1 cancels in the corr ratio.
    //     C/D layout: col = lane&31, row = (reg&3) + 8*(reg>>2) + 4*(lane>>5) ---
    constexpr float invT = 1.0f / 256.0f;
    if (ti == tj) {
        const int needHalf = (r32 >> 2) & 1;
        if (half == needHalf) {
            const int reg = ((r32 >> 3) << 2) | (r32 & 3);
            float gd = acc[0];
#pragma unroll
            for (int rr = 1; rr < 16; ++rr)
                if (rr == reg) gd = acc[rr];
            const int cg = 32 * ti + r32;
            const float cs = colsum[cg];
            const float raw = gd - cs * cs * invT;   // 255 * var
            rdiag[cg] = rsqrtf(fmaxf(raw, 1e-36f));
        }
    }
    __syncthreads();                               // barrier 3: rdiag ready

    // --- normalize, clip, store ---
    float* outb = out + (size_t)blk * (CC * CC);
    const int col = 32 * tj + r32;
    const float qc  = colsum[col] * invT;
    const float rdc = rdiag[col];
#pragma unroll
    for (int rr = 0; rr < 16; ++rr) {
        const int row = 32 * ti + (rr & 3) + 8 * (rr >> 2) + 4 * half;
        const float cv = acc[rr] - colsum[row] * qc;
        float cr = cv * rdiag[row] * rdc;
        cr = fminf(1.0f, fmaxf(-1.0f, cr));
        outb[row * CC + col] = cr;
    }
}

extern "C" void kernel_launch(void* const* d_in, const int* in_sizes, int n_in,
                              void* d_out, int out_size, void* d_ws, size_t ws_size,
                              hipStream_t stream) {
    const float* x     = (const float*)d_in[0];
    const float* alpha = (const float*)d_in[1];
    float* out = (float*)d_out;
    (void)d_ws; (void)ws_size;

    corr_kernel<<<16 * NW, 256, 0, stream>>>(x, alpha, out);
}